// Round 8
// baseline (11645.296 us; speedup 1.0000x reference)
//
#include <hip/hip_runtime.h>
#include <math.h>

// Problem: MPMatcher  S=6, B=16, L=8, M=256, K=128
// Phase 1: cost[b][m][k] f32. Final mean(0) as sum * (1/6) — XLA rewrites
//          divide-by-constant to multiply-by-reciprocal; this is the one
//          dense 1-ulp knob untested across R0-R5 (all pinned at absmax 39).
// Phase 2: the reference's (buggy) greedy walk, exact f64 replication
//          (R6 proved expected == buggy-greedy: correct JV scored 250).

#define S_ 6
#define B_ 16
#define L_ 8
#define M_ 256
#define K_ 128
#define NCOLS 256   // K real columns + (M-K) dummy zero columns (square pad)
#define NROWS 256   // = M

// ---------------------------------------------------------------- cost kernel
__global__ void cost_kernel(const float* __restrict__ mp,   // (6,16,8,256,2)
                            const float* __restrict__ mv,   // (6,16,256,1)
                            const float* __restrict__ gt,   // (6,16,128,2)
                            const float* __restrict__ gv,   // (6,16,128,1)
                            float* __restrict__ cost)       // (16,256,128)
{
#pragma clang fp contract(off)
    const int b = blockIdx.x;    // 16
    const int m = blockIdx.y;    // 256
    const int k = threadIdx.x;   // 128

    float accS = 0.0f;
    for (int s = 0; s < S_; ++s) {
        const int sb = s * B_ + b;
        const float gx = gt[(sb * K_ + k) * 2 + 0];
        const float gy = gt[(sb * K_ + k) * 2 + 1];
        float accL = 0.0f;
#pragma unroll
        for (int l = 0; l < L_; ++l) {
            const int base = ((sb * L_ + l) * M_ + m) * 2;
            const float dx = fabsf(mp[base + 0] - gx);
            const float dy = fabsf(mp[base + 1] - gy);
            const float diff = dx + dy;                       // |dx|+|dy|
            const float dl = (float)(L_ - (l + 1)) * 0.05f;   // (7-l)*f32(0.05)
            const float t = diff - dl;
            accL += fmaxf(t, 0.0f);                           // relu; seq l=0..7
        }
        const float meanL = accL * 0.125f;                    // /8 exact
        const float mvv = mv[sb * M_ + m];
        const float gtv = gv[sb * K_ + k];                    // exactly 0.0 or 1.0
        const float lp = -logf(mvv);                          // -log(mv)  (ocml)
        const float ln = -logf(1.0f - mvv);                   // -log(1-mv)
        const float val = (gtv != 0.0f) ? (5.0f * meanL + lp) : ln;  // exact select
        accS += val;                                          // seq s=0..5
    }
    cost[(b * M_ + m) * K_ + k] = accS * (1.0f / 6.0f);       // mean(0): * reciprocal
}

// ------------------------------------------------------------- matcher kernel
// One wave (64 lanes) per batch. Lane owns columns j = 1+lane+64r, r=0..3.
// r=0,1 -> real columns (cost from global), r=2,3 -> dummy columns (cost 0).
// Exact replication of the reference's dead-store greedy walk (f64).
__global__ __launch_bounds__(64, 1) void match_kernel(const float* __restrict__ cost,
                                                      int* __restrict__ out)
{
#pragma clang fp contract(off)
    const int b = blockIdx.x;
    const int lane = threadIdx.x;   // 0..63
    const float* C = cost + (size_t)b * NROWS * K_;
    const double INF = __builtin_inf();

    __shared__ double u_lds[NROWS + 1];   // u[0..256], 1-based rows
    __shared__ int    p_lds[NCOLS + 1];   // p[0..256], 1-based cols; 0 = unmatched

    for (int t = lane; t <= NROWS; t += 64) u_lds[t] = 0.0;
    for (int t = lane; t <= NCOLS; t += 64) p_lds[t] = 0;
    __syncthreads();

    double v[4] = {0.0, 0.0, 0.0, 0.0};

    for (int i = 1; i <= NROWS; ++i) {
        // ---- row start: refresh per-column caches (p static during walk;
        //      u[p[j]] for free j is never updated mid-walk)
        bool used[4] = {false, false, false, false};
        int pj[4];
        double upj[4];
#pragma unroll
        for (int r = 0; r < 4; ++r) pj[r] = p_lds[1 + lane + 64 * r];
#pragma unroll
        for (int r = 0; r < 4; ++r) upj[r] = u_lds[pj[r]];

        int i0 = i;            // p[0] = i (virtual column 0)
        double u_i0 = 0.0;     // u[i] == 0 at row start, always
        int j0 = 0;
        int j1 = 0;
        double usum = 0.0;     // accumulates u[i] updates (virtual col 0 used)

        while (true) {
            // mark used[j0] (ref: used[j0]=True at loop top; j0==0 via usum)
            if (j0 != 0) {
                const int t = j0 - 1;
                if ((t & 63) == lane) used[t >> 6] = true;
            }
            // candidates: cur = (cost - u[i0]) - v   (exact ref op order, f64)
            const double c0 = (double)C[(i0 - 1) * K_ + lane];
            const double c1 = (double)C[(i0 - 1) * K_ + 64 + lane];
            double cand0 = used[0] ? INF : ((c0 - u_i0) - v[0]);
            double cand1 = used[1] ? INF : ((c1 - u_i0) - v[1]);
            double cand2 = used[2] ? INF : ((0.0 - u_i0) - v[2]);
            double cand3 = used[3] ? INF : ((0.0 - u_i0) - v[3]);

            // local argmin over r (ascending j => '<' keeps first index on ties)
            double bv = cand0; int bj = 1 + lane;
            if (cand1 < bv) { bv = cand1; bj = 1 + lane + 64; }
            if (cand2 < bv) { bv = cand2; bj = 1 + lane + 128; }
            if (cand3 < bv) { bv = cand3; bj = 1 + lane + 192; }

            // wave butterfly argmin with first-index tie-break
#pragma unroll
            for (int off = 1; off < 64; off <<= 1) {
                const double ov = __shfl_xor(bv, off);
                const int    oj = __shfl_xor(bj, off);
                if (ov < bv || (ov == bv && oj < bj)) { bv = ov; bj = oj; }
            }
            const double delta = bv;
            j1 = bj;

            // potential updates (same order as ref: all used cols + virtual 0)
            usum += delta;   // u[i] += delta (virtual column 0)
#pragma unroll
            for (int r = 0; r < 4; ++r) {
                if (used[r]) { u_lds[pj[r]] += delta; v[r] -= delta; }
            }

            // broadcast p[j1], u[p[j1]] from owning lane's row-start caches
            const int t1 = j1 - 1;
            const int r1 = t1 >> 6;
            const int src = t1 & 63;
            const int    psel = (r1 == 0) ? pj[0] : (r1 == 1) ? pj[1] : (r1 == 2) ? pj[2] : pj[3];
            const double usel = (r1 == 0) ? upj[0] : (r1 == 1) ? upj[1] : (r1 == 2) ? upj[2] : upj[3];
            const int    i0n = __shfl(psel, src);
            const double u_n = __shfl(usel, src);
            if (i0n == 0) break;     // p[j1]==0 -> augment (way==0 => p[j1]=i)
            i0 = i0n;
            u_i0 = u_n;
            j0 = j1;
        }

        // assignment + commit u[i]
        if (lane == 0) {
            p_lds[j1] = i;
            u_lds[i] = usum;   // u[i] was 0 before this row
        }
        __syncthreads();
    }

    // out[b][k] = p[k+1] - 1   for the K real columns
    for (int j = 1 + lane; j <= K_; j += 64)
        out[b * K_ + (j - 1)] = p_lds[j] - 1;
}

// ------------------------------------------------------------------- launcher
extern "C" void kernel_launch(void* const* d_in, const int* in_sizes, int n_in,
                              void* d_out, int out_size, void* d_ws, size_t ws_size,
                              hipStream_t stream) {
    const float* mp = (const float*)d_in[0];   // meta_points
    const float* mv = (const float*)d_in[1];   // meta_visibles
    /* d_in[2] covisibles: unused by reference */
    const float* gt = (const float*)d_in[3];   // gtpoints
    const float* gv = (const float*)d_in[4];   // gtvisibles
    int* out = (int*)d_out;                    // int32 assignment indices
    float* cost = (float*)d_ws;                // 16*256*128 fp32 = 2 MB

    dim3 gridA(B_, M_);
    cost_kernel<<<gridA, K_, 0, stream>>>(mp, mv, gt, gv, cost);
    match_kernel<<<B_, 64, 0, stream>>>(cost, out);
}

// Round 9
// 2380.058 us; speedup vs baseline: 4.8929x; 4.8929x over previous
//
#include <hip/hip_runtime.h>
#include <math.h>

// Problem: MPMatcher  S=6, B=16, L=8, M=256, K=128
// Phase 1 (PASSING, DO NOT TOUCH): cost f32, ocml logf, *(1/6) reciprocal mean.
// Phase 2: reference's buggy greedy walk, f64-exact, now with:
//   - DPP (VALU-pipe) lexicographic argmin ladder instead of ds-based shfl_xor
//   - readlane scalar broadcasts instead of ds_bpermute
//   - rows 1..128 pre-matched to dummy cols (provably delta==0, state-identical)
//   - lane owns col pairs -> single dwordx2 row load

#define S_ 6
#define B_ 16
#define L_ 8
#define M_ 256
#define K_ 128

// ---------------------------------------------------------------- cost kernel
__global__ void cost_kernel(const float* __restrict__ mp,   // (6,16,8,256,2)
                            const float* __restrict__ mv,   // (6,16,256,1)
                            const float* __restrict__ gt,   // (6,16,128,2)
                            const float* __restrict__ gv,   // (6,16,128,1)
                            float* __restrict__ cost)       // (16,256,128)
{
#pragma clang fp contract(off)
    const int b = blockIdx.x;
    const int m = blockIdx.y;
    const int k = threadIdx.x;

    float accS = 0.0f;
    for (int s = 0; s < S_; ++s) {
        const int sb = s * B_ + b;
        const float gx = gt[(sb * K_ + k) * 2 + 0];
        const float gy = gt[(sb * K_ + k) * 2 + 1];
        float accL = 0.0f;
#pragma unroll
        for (int l = 0; l < L_; ++l) {
            const int base = ((sb * L_ + l) * M_ + m) * 2;
            const float dx = fabsf(mp[base + 0] - gx);
            const float dy = fabsf(mp[base + 1] - gy);
            const float diff = dx + dy;
            const float dl = (float)(L_ - (l + 1)) * 0.05f;
            const float t = diff - dl;
            accL += fmaxf(t, 0.0f);
        }
        const float meanL = accL * 0.125f;
        const float mvv = mv[sb * M_ + m];
        const float gtv = gv[sb * K_ + k];
        const float lp = -logf(mvv);
        const float ln = -logf(1.0f - mvv);
        const float val = (gtv != 0.0f) ? (5.0f * meanL + lp) : ln;
        accS += val;
    }
    cost[(b * M_ + m) * K_ + k] = accS * (1.0f / 6.0f);
}

// --------------------------------------------------------------- bit helpers
__device__ __forceinline__ double bits2d(int lo, int hi) {
    const unsigned long long u =
        ((unsigned long long)(unsigned)hi << 32) | (unsigned)lo;
    return __longlong_as_double((long long)u);
}
__device__ __forceinline__ void d2bits(double d, int& lo, int& hi) {
    const unsigned long long u = (unsigned long long)__double_as_longlong(d);
    lo = (int)(u & 0xffffffffull);
    hi = (int)(u >> 32);
}

// ------------------------------------------------------------- matcher kernel
// One wave per batch. Lane owns real cols j=2*lane+1, 2*lane+2 (slots 0,1)
// and dummy cols j=2*lane+129, 2*lane+130 (slots 2,3).
__global__ __launch_bounds__(64, 1) void match_kernel(const float* __restrict__ cost,
                                                      int* __restrict__ out)
{
#pragma clang fp contract(off)
    const int b = blockIdx.x;
    const int lane = threadIdx.x;   // 0..63
    const float* C = cost + (size_t)b * M_ * K_;
    const double INF = __builtin_inf();

    __shared__ double u_lds[257];   // u[0..256], 1-based rows
    __shared__ int    p_lds[257];   // p[j] = row matched to col j; 0 = free

    // rows 1..128 pre-matched to dummy cols 129..256 (exact: all deltas 0,
    // u/v untouched, net state p[128+i]=i — proven vs the reference walk)
    for (int t = lane; t < 257; t += 64) {
        u_lds[t] = 0.0;
        p_lds[t] = (t >= 129) ? (t - 128) : 0;
    }
    __syncthreads();

    double v0 = 0.0, v1 = 0.0, v2 = 0.0, v3 = 0.0;  // column potentials

    for (int i = 129; i <= 256; ++i) {
        // row-start caches (p static during walk; u[p[j]] for free j never
        // updated mid-walk -> row-start snapshot valid for broadcasts)
        int used = 0;
        const int pj0 = p_lds[2 * lane + 1];
        const int pj1 = p_lds[2 * lane + 2];
        const int pj2 = p_lds[2 * lane + 129];
        const int pj3 = p_lds[2 * lane + 130];
        const double up0 = u_lds[pj0], up1 = u_lds[pj1];
        const double up2 = u_lds[pj2], up3 = u_lds[pj3];

        int i0 = i;
        double u_i0 = 0.0;
        int j0 = 0, j1 = 0;
        double usum = 0.0;

        for (;;) {
            // mark used[j0] (j0==0 is the virtual column -> usum)
            if (j0 != 0) {
                int ol, sl;
                if (j0 >= 129) { ol = (j0 - 129) >> 1; sl = 2 + ((j0 - 129) & 1); }
                else           { ol = (j0 - 1) >> 1;   sl = (j0 - 1) & 1; }
                if (lane == ol) used |= (1 << sl);
            }

            // candidates: cur = (cost - u[i0]) - v   (exact ref op order, f64)
            const float2 cc = *(const float2*)(C + (size_t)(i0 - 1) * K_ + 2 * lane);
            double cd0 = ((double)cc.x - u_i0) - v0;
            double cd1 = ((double)cc.y - u_i0) - v1;
            double cd2 = (0.0 - u_i0) - v2;
            double cd3 = (0.0 - u_i0) - v3;
            if (used & 1) cd0 = INF;
            if (used & 2) cd1 = INF;
            if (used & 4) cd2 = INF;
            if (used & 8) cd3 = INF;

            // local argmin; slot order is ascending j for this lane
            double bv = cd0; int bj = 2 * lane + 1;
            if (cd1 < bv) { bv = cd1; bj = 2 * lane + 2; }
            if (cd2 < bv) { bv = cd2; bj = 2 * lane + 129; }
            if (cd3 < bv) { bv = cd3; bj = 2 * lane + 130; }

            // wave argmin via DPP ladder (VALU pipe). Lexicographic (val, j)
            // min is associative+commutative -> any covering tree is exact.
            int lo, hi; d2bits(bv, lo, hi);
            int idx = bj;
#define AM_STAGE(CTRL, RM)                                                       \
            {                                                                    \
                const int nlo = __builtin_amdgcn_update_dpp(lo, lo, CTRL, RM, 0xf, false);  \
                const int nhi = __builtin_amdgcn_update_dpp(hi, hi, CTRL, RM, 0xf, false);  \
                const int nix = __builtin_amdgcn_update_dpp(idx, idx, CTRL, RM, 0xf, false);\
                const double nv = bits2d(nlo, nhi);                              \
                const double cv = bits2d(lo, hi);                                \
                const bool take = (nv < cv) || (nv == cv && nix < idx);          \
                lo = take ? nlo : lo; hi = take ? nhi : hi; idx = take ? nix : idx; \
            }
            AM_STAGE(0x111, 0xf)   // row_shr:1
            AM_STAGE(0x112, 0xf)   // row_shr:2
            AM_STAGE(0x114, 0xf)   // row_shr:4
            AM_STAGE(0x118, 0xf)   // row_shr:8
            AM_STAGE(0x142, 0xa)   // row_bcast:15 -> rows 1,3
            AM_STAGE(0x143, 0xc)   // row_bcast:31 -> rows 2,3
#undef AM_STAGE
            j1 = __builtin_amdgcn_readlane(idx, 63);
            const double delta = bits2d(__builtin_amdgcn_readlane(lo, 63),
                                        __builtin_amdgcn_readlane(hi, 63));

            // potential updates (ref order: all used cols + virtual col 0)
            usum += delta;
            if (used & 1) { u_lds[pj0] += delta; v0 -= delta; }
            if (used & 2) { u_lds[pj1] += delta; v1 -= delta; }
            if (used & 4) { u_lds[pj2] += delta; v2 -= delta; }
            if (used & 8) { u_lds[pj3] += delta; v3 -= delta; }

            // broadcast p[j1], u[p[j1]] from owner lane's row-start caches
            int ol, sl;
            if (j1 >= 129) { ol = (j1 - 129) >> 1; sl = 2 + ((j1 - 129) & 1); }
            else           { ol = (j1 - 1) >> 1;   sl = (j1 - 1) & 1; }
            const int    psel = (sl == 0) ? pj0 : (sl == 1) ? pj1 : (sl == 2) ? pj2 : pj3;
            const double usel = (sl == 0) ? up0 : (sl == 1) ? up1 : (sl == 2) ? up2 : up3;
            const int i0n = __builtin_amdgcn_readlane(psel, ol);
            int ulo, uhi; d2bits(usel, ulo, uhi);
            const double u_n = bits2d(__builtin_amdgcn_readlane(ulo, ol),
                                      __builtin_amdgcn_readlane(uhi, ol));
            if (i0n == 0) break;    // free column -> augment (way==0 => p[j1]=i)
            i0 = i0n;
            u_i0 = u_n;
            j0 = j1;
        }

        __syncthreads();
        if (lane == 0) { p_lds[j1] = i; u_lds[i] = usum; }
        __syncthreads();
    }

    // out[b][k] = p[k+1] - 1 for the K real columns
    for (int j = lane; j < K_; j += 64)
        out[b * K_ + j] = p_lds[j + 1] - 1;
}

// ------------------------------------------------------------------- launcher
extern "C" void kernel_launch(void* const* d_in, const int* in_sizes, int n_in,
                              void* d_out, int out_size, void* d_ws, size_t ws_size,
                              hipStream_t stream) {
    const float* mp = (const float*)d_in[0];   // meta_points
    const float* mv = (const float*)d_in[1];   // meta_visibles
    /* d_in[2] covisibles: unused by reference */
    const float* gt = (const float*)d_in[3];   // gtpoints
    const float* gv = (const float*)d_in[4];   // gtvisibles
    int* out = (int*)d_out;                    // int32 assignment indices
    float* cost = (float*)d_ws;                // 16*256*128 fp32 = 2 MB

    dim3 gridA(B_, M_);
    cost_kernel<<<gridA, K_, 0, stream>>>(mp, mv, gt, gv, cost);
    match_kernel<<<B_, 64, 0, stream>>>(cost, out);
}

// Round 10
// 1519.855 us; speedup vs baseline: 7.6621x; 1.5660x over previous
//
#include <hip/hip_runtime.h>
#include <math.h>

// Problem: MPMatcher  S=6, B=16, L=8, M=256, K=128
// Phase 1 (PASSING, DO NOT TOUCH): cost f32, ocml logf, *(1/6) reciprocal mean.
// Phase 2: reference's buggy greedy walk, f64-exact. R9 chain cuts:
//   - value-only f64 DPP min ladder + ballot/ctz first-index extraction
//   - per-lane register u accumulation (no in-loop LDS RMW), commit at walk end
//   - row load issued at loop top, bookkeeping hidden under its latency
//   - rows 1..128 pre-matched to dummies (proven exact, R8)

#define S_ 6
#define B_ 16
#define L_ 8
#define M_ 256
#define K_ 128

// ---------------------------------------------------------------- cost kernel
__global__ void cost_kernel(const float* __restrict__ mp,   // (6,16,8,256,2)
                            const float* __restrict__ mv,   // (6,16,256,1)
                            const float* __restrict__ gt,   // (6,16,128,2)
                            const float* __restrict__ gv,   // (6,16,128,1)
                            float* __restrict__ cost)       // (16,256,128)
{
#pragma clang fp contract(off)
    const int b = blockIdx.x;
    const int m = blockIdx.y;
    const int k = threadIdx.x;

    float accS = 0.0f;
    for (int s = 0; s < S_; ++s) {
        const int sb = s * B_ + b;
        const float gx = gt[(sb * K_ + k) * 2 + 0];
        const float gy = gt[(sb * K_ + k) * 2 + 1];
        float accL = 0.0f;
#pragma unroll
        for (int l = 0; l < L_; ++l) {
            const int base = ((sb * L_ + l) * M_ + m) * 2;
            const float dx = fabsf(mp[base + 0] - gx);
            const float dy = fabsf(mp[base + 1] - gy);
            const float diff = dx + dy;
            const float dl = (float)(L_ - (l + 1)) * 0.05f;
            const float t = diff - dl;
            accL += fmaxf(t, 0.0f);
        }
        const float meanL = accL * 0.125f;
        const float mvv = mv[sb * M_ + m];
        const float gtv = gv[sb * K_ + k];
        const float lp = -logf(mvv);
        const float ln = -logf(1.0f - mvv);
        const float val = (gtv != 0.0f) ? (5.0f * meanL + lp) : ln;
        accS += val;
    }
    cost[(b * M_ + m) * K_ + k] = accS * (1.0f / 6.0f);
}

// --------------------------------------------------------------- bit helpers
__device__ __forceinline__ double bits2d(int lo, int hi) {
    const unsigned long long u =
        ((unsigned long long)(unsigned)hi << 32) | (unsigned)lo;
    return __longlong_as_double((long long)u);
}
__device__ __forceinline__ void d2bits(double d, int& lo, int& hi) {
    const unsigned long long u = (unsigned long long)__double_as_longlong(d);
    lo = (int)(u & 0xffffffffull);
    hi = (int)(u >> 32);
}

// ------------------------------------------------------------- matcher kernel
// One wave per batch. Lane owns real cols j=2*lane+1, 2*lane+2 (slots 0,1)
// and dummy cols j=2*lane+129, 2*lane+130 (slots 2,3).
__global__ __launch_bounds__(64, 1) void match_kernel(const float* __restrict__ cost,
                                                      int* __restrict__ out)
{
#pragma clang fp contract(off)
    const int b = blockIdx.x;
    const int lane = threadIdx.x;   // 0..63
    const float* C = cost + (size_t)b * M_ * K_;
    const double INF = __builtin_inf();
    const int BIG = 0x7fffffff;

    __shared__ double u_lds[257];   // u[0..256], 1-based rows
    __shared__ int    p_lds[257];   // p[j] = row matched to col j; 0 = free

    // rows 1..128 pre-matched to dummy cols 129..256 (exact, proven R8)
    for (int t = lane; t < 257; t += 64) {
        u_lds[t] = 0.0;
        p_lds[t] = (t >= 129) ? (t - 128) : 0;
    }
    __syncthreads();

    double v0 = 0.0, v1 = 0.0, v2 = 0.0, v3 = 0.0;  // column potentials

    for (int i = 129; i <= 256; ++i) {
        // ---- row start: snapshot caches. p static during walk; u[p[j]] for a
        // free col's row is never updated mid-walk (p injective) -> snapshot
        // valid for broadcasts. ur* = running u value (ref add order).
        int used = 0;
        const int pj0 = p_lds[2 * lane + 1];
        const int pj1 = p_lds[2 * lane + 2];
        const int pj2 = p_lds[2 * lane + 129];
        const int pj3 = p_lds[2 * lane + 130];
        double ur0 = u_lds[pj0], ur1 = u_lds[pj1];
        double ur2 = u_lds[pj2], ur3 = u_lds[pj3];
        const double up0 = ur0, up1 = ur1, up2 = ur2, up3 = ur3;

        int i0 = i;
        double u_i0 = 0.0;
        int j0 = 0, j1 = 0;
        double usum = 0.0;

        for (;;) {
            // issue the row load first; bookkeeping runs under its latency
            const float2 cc = *(const float2*)(C + (size_t)(i0 - 1) * K_ + 2 * lane);

            // mark used[j0] (j0==0 is the virtual column -> usum)
            if (j0 != 0) {
                int ol, sl;
                if (j0 >= 129) { ol = (j0 - 129) >> 1; sl = 2 + ((j0 - 129) & 1); }
                else           { ol = (j0 - 1) >> 1;   sl = (j0 - 1) & 1; }
                if (lane == ol) used |= (1 << sl);
            }

            // candidates: cur = (cost - u[i0]) - v   (exact ref op order, f64)
            double cd0 = ((double)cc.x - u_i0) - v0;
            double cd1 = ((double)cc.y - u_i0) - v1;
            double cd2 = (0.0 - u_i0) - v2;
            double cd3 = (0.0 - u_i0) - v3;
            if (used & 1) cd0 = INF;
            if (used & 2) cd1 = INF;
            if (used & 4) cd2 = INF;
            if (used & 8) cd3 = INF;

            // local value min (bits: one of the operands; +-0 ambiguity harmless)
            const double m01 = fmin(cd0, cd1);
            const double m23 = fmin(cd2, cd3);
            double bv = fmin(m01, m23);

            // wave value-min via DPP ladder (VALU pipe), result in lane 63
            int lo, hi; d2bits(bv, lo, hi);
#define MIN_STAGE(CTRL, RM)                                                      \
            {                                                                    \
                const int nlo = __builtin_amdgcn_update_dpp(lo, lo, CTRL, RM, 0xf, false); \
                const int nhi = __builtin_amdgcn_update_dpp(hi, hi, CTRL, RM, 0xf, false); \
                const double mv2 = fmin(bits2d(lo, hi), bits2d(nlo, nhi));       \
                d2bits(mv2, lo, hi);                                             \
            }
            MIN_STAGE(0x111, 0xf)   // row_shr:1
            MIN_STAGE(0x112, 0xf)   // row_shr:2
            MIN_STAGE(0x114, 0xf)   // row_shr:4
            MIN_STAGE(0x118, 0xf)   // row_shr:8
            MIN_STAGE(0x142, 0xa)   // row_bcast:15 -> rows 1,3
            MIN_STAGE(0x143, 0xc)   // row_bcast:31 -> rows 2,3
#undef MIN_STAGE
            const int mlo = __builtin_amdgcn_readlane(lo, 63);
            const int mhi = __builtin_amdgcn_readlane(hi, 63);
            const double delta = bits2d(mlo, mhi);   // == min value (scalar)

            // first-index extraction: cd == delta marks min-achievers; lane
            // order == j order within each class; real js (<=128) < dummy js
            int jr = BIG;
            if (cd1 == delta) jr = 2 * lane + 2;
            if (cd0 == delta) jr = 2 * lane + 1;
            int jd = BIG;
            if (cd3 == delta) jd = 2 * lane + 130;
            if (cd2 == delta) jd = 2 * lane + 129;
            const unsigned long long br = __ballot(jr != BIG);
            if (br != 0ull) {
                j1 = __builtin_amdgcn_readlane(jr, (int)__builtin_ctzll(br));
            } else {
                const unsigned long long bd = __ballot(jd != BIG);
                j1 = __builtin_amdgcn_readlane(jd, (int)__builtin_ctzll(bd));
            }

            // potential updates (ref order; u now in registers, commit at end)
            usum += delta;
            if (used & 1) { ur0 += delta; v0 -= delta; }
            if (used & 2) { ur1 += delta; v1 -= delta; }
            if (used & 4) { ur2 += delta; v2 -= delta; }
            if (used & 8) { ur3 += delta; v3 -= delta; }

            // broadcast p[j1], u[p[j1]] from owner lane's row-start snapshot
            int ol, sl;
            if (j1 >= 129) { ol = (j1 - 129) >> 1; sl = 2 + ((j1 - 129) & 1); }
            else           { ol = (j1 - 1) >> 1;   sl = (j1 - 1) & 1; }
            const int    psel = (sl == 0) ? pj0 : (sl == 1) ? pj1 : (sl == 2) ? pj2 : pj3;
            const double usel = (sl == 0) ? up0 : (sl == 1) ? up1 : (sl == 2) ? up2 : up3;
            const int i0n = __builtin_amdgcn_readlane(psel, ol);
            int ulo, uhi; d2bits(usel, ulo, uhi);
            const double u_n = bits2d(__builtin_amdgcn_readlane(ulo, ol),
                                      __builtin_amdgcn_readlane(uhi, ol));
            if (i0n == 0) break;    // free column -> augment (way==0 => p[j1]=i)
            i0 = i0n;
            u_i0 = u_n;
            j0 = j1;
        }

        // ---- commit: marked slots write their running u; lane 0 augments
        __syncthreads();
        if (used & 1) u_lds[pj0] = ur0;
        if (used & 2) u_lds[pj1] = ur1;
        if (used & 4) u_lds[pj2] = ur2;
        if (used & 8) u_lds[pj3] = ur3;
        if (lane == 0) { p_lds[j1] = i; u_lds[i] = usum; }
        __syncthreads();
    }

    // out[b][k] = p[k+1] - 1 for the K real columns
    for (int j = lane; j < K_; j += 64)
        out[b * K_ + j] = p_lds[j + 1] - 1;
}

// ------------------------------------------------------------------- launcher
extern "C" void kernel_launch(void* const* d_in, const int* in_sizes, int n_in,
                              void* d_out, int out_size, void* d_ws, size_t ws_size,
                              hipStream_t stream) {
    const float* mp = (const float*)d_in[0];   // meta_points
    const float* mv = (const float*)d_in[1];   // meta_visibles
    /* d_in[2] covisibles: unused by reference */
    const float* gt = (const float*)d_in[3];   // gtpoints
    const float* gv = (const float*)d_in[4];   // gtvisibles
    int* out = (int*)d_out;                    // int32 assignment indices
    float* cost = (float*)d_ws;                // 16*256*128 fp32 = 2 MB

    dim3 gridA(B_, M_);
    cost_kernel<<<gridA, K_, 0, stream>>>(mp, mv, gt, gv, cost);
    match_kernel<<<B_, 64, 0, stream>>>(cost, out);
}

// Round 11
// 1428.225 us; speedup vs baseline: 8.1537x; 1.0642x over previous
//
#include <hip/hip_runtime.h>
#include <math.h>

// Problem: MPMatcher  S=6, B=16, L=8, M=256, K=128
// Phase 1 (PASSING, DO NOT TOUCH): cost f32, ocml logf, *(1/6) reciprocal mean.
// Phase 2: reference's buggy greedy walk, f64-exact. R10: cost slab staged in
//   LDS (128 KB, row-major) -> in-loop row read is ds_read_b64 (~120cy) not
//   L2 global (~200cy). Value-only DPP min ladder + ballot extraction (R9),
//   register u accumulation (R9), rows 1..128 pre-matched (R8).

#define S_ 6
#define B_ 16
#define L_ 8
#define M_ 256
#define K_ 128

// ---------------------------------------------------------------- cost kernel
__global__ void cost_kernel(const float* __restrict__ mp,   // (6,16,8,256,2)
                            const float* __restrict__ mv,   // (6,16,256,1)
                            const float* __restrict__ gt,   // (6,16,128,2)
                            const float* __restrict__ gv,   // (6,16,128,1)
                            float* __restrict__ cost)       // (16,256,128)
{
#pragma clang fp contract(off)
    const int b = blockIdx.x;
    const int m = blockIdx.y;
    const int k = threadIdx.x;

    float accS = 0.0f;
    for (int s = 0; s < S_; ++s) {
        const int sb = s * B_ + b;
        const float gx = gt[(sb * K_ + k) * 2 + 0];
        const float gy = gt[(sb * K_ + k) * 2 + 1];
        float accL = 0.0f;
#pragma unroll
        for (int l = 0; l < L_; ++l) {
            const int base = ((sb * L_ + l) * M_ + m) * 2;
            const float dx = fabsf(mp[base + 0] - gx);
            const float dy = fabsf(mp[base + 1] - gy);
            const float diff = dx + dy;
            const float dl = (float)(L_ - (l + 1)) * 0.05f;
            const float t = diff - dl;
            accL += fmaxf(t, 0.0f);
        }
        const float meanL = accL * 0.125f;
        const float mvv = mv[sb * M_ + m];
        const float gtv = gv[sb * K_ + k];
        const float lp = -logf(mvv);
        const float ln = -logf(1.0f - mvv);
        const float val = (gtv != 0.0f) ? (5.0f * meanL + lp) : ln;
        accS += val;
    }
    cost[(b * M_ + m) * K_ + k] = accS * (1.0f / 6.0f);
}

// --------------------------------------------------------------- bit helpers
__device__ __forceinline__ double bits2d(int lo, int hi) {
    const unsigned long long u =
        ((unsigned long long)(unsigned)hi << 32) | (unsigned)lo;
    return __longlong_as_double((long long)u);
}
__device__ __forceinline__ void d2bits(double d, int& lo, int& hi) {
    const unsigned long long u = (unsigned long long)__double_as_longlong(d);
    lo = (int)(u & 0xffffffffull);
    hi = (int)(u >> 32);
}

// ------------------------------------------------------------- matcher kernel
// One wave per batch. Lane owns real cols j=2*lane+1, 2*lane+2 (slots 0,1)
// and dummy cols j=2*lane+129, 2*lane+130 (slots 2,3).
__global__ __launch_bounds__(64, 1) void match_kernel(const float* __restrict__ cost,
                                                      int* __restrict__ out)
{
#pragma clang fp contract(off)
    const int b = blockIdx.x;
    const int lane = threadIdx.x;   // 0..63
    const float* C = cost + (size_t)b * M_ * K_;
    const double INF = __builtin_inf();
    const int BIG = 0x7fffffff;

    __shared__ float  C_lds[M_ * K_];   // 128 KB cost slab (row-major, = global)
    __shared__ double u_lds[257];       // u[0..256], 1-based rows
    __shared__ int    p_lds[257];       // p[j] = row matched to col j; 0 = free

    // stage the batch's cost slab into LDS (coalesced float4 copies)
    for (int t = lane; t < (M_ * K_) / 4; t += 64)
        ((float4*)C_lds)[t] = ((const float4*)C)[t];

    // rows 1..128 pre-matched to dummy cols 129..256 (exact, proven R8)
    for (int t = lane; t < 257; t += 64) {
        u_lds[t] = 0.0;
        p_lds[t] = (t >= 129) ? (t - 128) : 0;
    }
    __syncthreads();

    double v0 = 0.0, v1 = 0.0, v2 = 0.0, v3 = 0.0;  // column potentials

    for (int i = 129; i <= 256; ++i) {
        // ---- row start: snapshot caches. p static during walk; u[p[j]] for a
        // free col's row is never updated mid-walk (p injective) -> snapshot
        // valid for broadcasts. ur* = running u value (ref add order).
        int used = 0;
        const int pj0 = p_lds[2 * lane + 1];
        const int pj1 = p_lds[2 * lane + 2];
        const int pj2 = p_lds[2 * lane + 129];
        const int pj3 = p_lds[2 * lane + 130];
        double ur0 = u_lds[pj0], ur1 = u_lds[pj1];
        double ur2 = u_lds[pj2], ur3 = u_lds[pj3];
        const double up0 = ur0, up1 = ur1, up2 = ur2, up3 = ur3;

        int i0 = i;
        double u_i0 = 0.0;
        int j0 = 0, j1 = 0;
        double usum = 0.0;

        for (;;) {
            // row read from LDS (issued first; bookkeeping under its latency)
            const float2 cc = *(const float2*)(C_lds + (i0 - 1) * K_ + 2 * lane);

            // mark used[j0] (j0==0 is the virtual column -> usum)
            if (j0 != 0) {
                int ol, sl;
                if (j0 >= 129) { ol = (j0 - 129) >> 1; sl = 2 + ((j0 - 129) & 1); }
                else           { ol = (j0 - 1) >> 1;   sl = (j0 - 1) & 1; }
                if (lane == ol) used |= (1 << sl);
            }

            // candidates: cur = (cost - u[i0]) - v   (exact ref op order, f64)
            double cd0 = ((double)cc.x - u_i0) - v0;
            double cd1 = ((double)cc.y - u_i0) - v1;
            double cd2 = (0.0 - u_i0) - v2;
            double cd3 = (0.0 - u_i0) - v3;
            if (used & 1) cd0 = INF;
            if (used & 2) cd1 = INF;
            if (used & 4) cd2 = INF;
            if (used & 8) cd3 = INF;

            // local value min (bits: one of the operands; +-0 ambiguity harmless)
            const double m01 = fmin(cd0, cd1);
            const double m23 = fmin(cd2, cd3);
            double bv = fmin(m01, m23);

            // wave value-min via DPP ladder (VALU pipe), result in lane 63
            int lo, hi; d2bits(bv, lo, hi);
#define MIN_STAGE(CTRL, RM)                                                      \
            {                                                                    \
                const int nlo = __builtin_amdgcn_update_dpp(lo, lo, CTRL, RM, 0xf, false); \
                const int nhi = __builtin_amdgcn_update_dpp(hi, hi, CTRL, RM, 0xf, false); \
                const double mv2 = fmin(bits2d(lo, hi), bits2d(nlo, nhi));       \
                d2bits(mv2, lo, hi);                                             \
            }
            MIN_STAGE(0x111, 0xf)   // row_shr:1
            MIN_STAGE(0x112, 0xf)   // row_shr:2
            MIN_STAGE(0x114, 0xf)   // row_shr:4
            MIN_STAGE(0x118, 0xf)   // row_shr:8
            MIN_STAGE(0x142, 0xa)   // row_bcast:15 -> rows 1,3
            MIN_STAGE(0x143, 0xc)   // row_bcast:31 -> rows 2,3
#undef MIN_STAGE
            const int mlo = __builtin_amdgcn_readlane(lo, 63);
            const int mhi = __builtin_amdgcn_readlane(hi, 63);
            const double delta = bits2d(mlo, mhi);   // == min value (scalar)

            // first-index extraction: cd == delta marks min-achievers; lane
            // order == j order within each class; real js (<=128) < dummy js
            int jr = BIG;
            if (cd1 == delta) jr = 2 * lane + 2;
            if (cd0 == delta) jr = 2 * lane + 1;
            int jd = BIG;
            if (cd3 == delta) jd = 2 * lane + 130;
            if (cd2 == delta) jd = 2 * lane + 129;
            const unsigned long long br = __ballot(jr != BIG);
            const unsigned long long bd = __ballot(jd != BIG);
            const unsigned long long bb = br ? br : bd;
            const int cand = (br != 0ull) ? jr : jd;   // uniform cond select
            j1 = __builtin_amdgcn_readlane(cand, (int)__builtin_ctzll(bb));

            // potential updates (ref order; u in registers, commit at end)
            usum += delta;
            if (used & 1) { ur0 += delta; v0 -= delta; }
            if (used & 2) { ur1 += delta; v1 -= delta; }
            if (used & 4) { ur2 += delta; v2 -= delta; }
            if (used & 8) { ur3 += delta; v3 -= delta; }

            // broadcast p[j1], u[p[j1]] from owner lane's row-start snapshot
            int ol, sl;
            if (j1 >= 129) { ol = (j1 - 129) >> 1; sl = 2 + ((j1 - 129) & 1); }
            else           { ol = (j1 - 1) >> 1;   sl = (j1 - 1) & 1; }
            const int    psel = (sl == 0) ? pj0 : (sl == 1) ? pj1 : (sl == 2) ? pj2 : pj3;
            const double usel = (sl == 0) ? up0 : (sl == 1) ? up1 : (sl == 2) ? up2 : up3;
            const int i0n = __builtin_amdgcn_readlane(psel, ol);
            int ulo, uhi; d2bits(usel, ulo, uhi);
            const double u_n = bits2d(__builtin_amdgcn_readlane(ulo, ol),
                                      __builtin_amdgcn_readlane(uhi, ol));
            if (i0n == 0) break;    // free column -> augment (way==0 => p[j1]=i)
            i0 = i0n;
            u_i0 = u_n;
            j0 = j1;
        }

        // ---- commit: marked slots write their running u; lane 0 augments
        __syncthreads();
        if (used & 1) u_lds[pj0] = ur0;
        if (used & 2) u_lds[pj1] = ur1;
        if (used & 4) u_lds[pj2] = ur2;
        if (used & 8) u_lds[pj3] = ur3;
        if (lane == 0) { p_lds[j1] = i; u_lds[i] = usum; }
        __syncthreads();
    }

    // out[b][k] = p[k+1] - 1 for the K real columns
    for (int j = lane; j < K_; j += 64)
        out[b * K_ + j] = p_lds[j + 1] - 1;
}

// ------------------------------------------------------------------- launcher
extern "C" void kernel_launch(void* const* d_in, const int* in_sizes, int n_in,
                              void* d_out, int out_size, void* d_ws, size_t ws_size,
                              hipStream_t stream) {
    const float* mp = (const float*)d_in[0];   // meta_points
    const float* mv = (const float*)d_in[1];   // meta_visibles
    /* d_in[2] covisibles: unused by reference */
    const float* gt = (const float*)d_in[3];   // gtpoints
    const float* gv = (const float*)d_in[4];   // gtvisibles
    int* out = (int*)d_out;                    // int32 assignment indices
    float* cost = (float*)d_ws;                // 16*256*128 fp32 = 2 MB

    dim3 gridA(B_, M_);
    cost_kernel<<<gridA, K_, 0, stream>>>(mp, mv, gt, gv, cost);
    match_kernel<<<B_, 64, 0, stream>>>(cost, out);
}

// Round 12
// 1418.884 us; speedup vs baseline: 8.2074x; 1.0066x over previous
//
#include <hip/hip_runtime.h>
#include <math.h>

// Problem: MPMatcher  S=6, B=16, L=8, M=256, K=128
// Phase 1 (PASSING, DO NOT TOUCH): cost f32, ocml logf, *(1/6) reciprocal mean.
// Phase 2: reference's buggy greedy walk, f64-exact. R11:
//   - dummy cols are never re-matched -> i0n = j1-128 without readlane
//   - software-pipelined row load: next ds_read issued right after i0n;
//     potential updates / u_n broadcast / used-marking run under its shadow
//     (final-iteration updates still applied before break, matching the ref)
//   - LDS cost slab (R10), value-DPP ladder + ballot extraction (R9),
//     register u accumulation (R9), rows 1..128 pre-matched (R8)

#define S_ 6
#define B_ 16
#define L_ 8
#define M_ 256
#define K_ 128

// ---------------------------------------------------------------- cost kernel
__global__ void cost_kernel(const float* __restrict__ mp,   // (6,16,8,256,2)
                            const float* __restrict__ mv,   // (6,16,256,1)
                            const float* __restrict__ gt,   // (6,16,128,2)
                            const float* __restrict__ gv,   // (6,16,128,1)
                            float* __restrict__ cost)       // (16,256,128)
{
#pragma clang fp contract(off)
    const int b = blockIdx.x;
    const int m = blockIdx.y;
    const int k = threadIdx.x;

    float accS = 0.0f;
    for (int s = 0; s < S_; ++s) {
        const int sb = s * B_ + b;
        const float gx = gt[(sb * K_ + k) * 2 + 0];
        const float gy = gt[(sb * K_ + k) * 2 + 1];
        float accL = 0.0f;
#pragma unroll
        for (int l = 0; l < L_; ++l) {
            const int base = ((sb * L_ + l) * M_ + m) * 2;
            const float dx = fabsf(mp[base + 0] - gx);
            const float dy = fabsf(mp[base + 1] - gy);
            const float diff = dx + dy;
            const float dl = (float)(L_ - (l + 1)) * 0.05f;
            const float t = diff - dl;
            accL += fmaxf(t, 0.0f);
        }
        const float meanL = accL * 0.125f;
        const float mvv = mv[sb * M_ + m];
        const float gtv = gv[sb * K_ + k];
        const float lp = -logf(mvv);
        const float ln = -logf(1.0f - mvv);
        const float val = (gtv != 0.0f) ? (5.0f * meanL + lp) : ln;
        accS += val;
    }
    cost[(b * M_ + m) * K_ + k] = accS * (1.0f / 6.0f);
}

// --------------------------------------------------------------- bit helpers
__device__ __forceinline__ double bits2d(int lo, int hi) {
    const unsigned long long u =
        ((unsigned long long)(unsigned)hi << 32) | (unsigned)lo;
    return __longlong_as_double((long long)u);
}
__device__ __forceinline__ void d2bits(double d, int& lo, int& hi) {
    const unsigned long long u = (unsigned long long)__double_as_longlong(d);
    lo = (int)(u & 0xffffffffull);
    hi = (int)(u >> 32);
}

// ------------------------------------------------------------- matcher kernel
// One wave per batch. Lane owns real cols j=2*lane+1, 2*lane+2 (slots 0,1)
// and dummy cols j=2*lane+129, 2*lane+130 (slots 2,3).
__global__ __launch_bounds__(64, 1) void match_kernel(const float* __restrict__ cost,
                                                      int* __restrict__ out)
{
#pragma clang fp contract(off)
    const int b = blockIdx.x;
    const int lane = threadIdx.x;   // 0..63
    const float* C = cost + (size_t)b * M_ * K_;
    const double INF = __builtin_inf();
    const int BIG = 0x7fffffff;

    __shared__ float  C_lds[M_ * K_];   // 128 KB cost slab (row-major, = global)
    __shared__ double u_lds[257];       // u[0..256], 1-based rows
    __shared__ int    p_lds[257];       // p[j] = row matched to col j; 0 = free

    // stage the batch's cost slab into LDS (coalesced float4 copies)
    for (int t = lane; t < (M_ * K_) / 4; t += 64)
        ((float4*)C_lds)[t] = ((const float4*)C)[t];

    // rows 1..128 pre-matched to dummy cols 129..256 (exact, proven R8)
    for (int t = lane; t < 257; t += 64) {
        u_lds[t] = 0.0;
        p_lds[t] = (t >= 129) ? (t - 128) : 0;
    }
    __syncthreads();

    double v0 = 0.0, v1 = 0.0, v2 = 0.0, v3 = 0.0;  // column potentials

    for (int i = 129; i <= 256; ++i) {
        // ---- row start: snapshot caches. p static during walk; dummies never
        // re-matched; u[p[j]] for free cols never updated mid-walk -> snapshot
        // valid for broadcasts. ur* = running u value (ref add order).
        int used = 0;
        const int pj0 = p_lds[2 * lane + 1];
        const int pj1 = p_lds[2 * lane + 2];
        const int pj2 = p_lds[2 * lane + 129];
        const int pj3 = p_lds[2 * lane + 130];
        double ur0 = u_lds[pj0], ur1 = u_lds[pj1];
        double ur2 = u_lds[pj2], ur3 = u_lds[pj3];
        const double up0 = ur0, up1 = ur1, up2 = ur2, up3 = ur3;

        float2 cc = *(const float2*)(C_lds + (i - 1) * K_ + 2 * lane);
        double u_i0 = 0.0;
        int j1 = 0;
        double usum = 0.0;

        for (;;) {
            // candidates: cur = (cost - u[i0]) - v   (exact ref op order, f64)
            double cd0 = ((double)cc.x - u_i0) - v0;
            double cd1 = ((double)cc.y - u_i0) - v1;
            double cd2 = (0.0 - u_i0) - v2;
            double cd3 = (0.0 - u_i0) - v3;
            if (used & 1) cd0 = INF;
            if (used & 2) cd1 = INF;
            if (used & 4) cd2 = INF;
            if (used & 8) cd3 = INF;

            // local value min (+-0 ambiguity harmless, proven R9/R10)
            const double m01 = fmin(cd0, cd1);
            const double m23 = fmin(cd2, cd3);
            double bv = fmin(m01, m23);

            // wave value-min via DPP ladder (VALU pipe), result in lane 63
            int lo, hi; d2bits(bv, lo, hi);
#define MIN_STAGE(CTRL, RM)                                                      \
            {                                                                    \
                const int nlo = __builtin_amdgcn_update_dpp(lo, lo, CTRL, RM, 0xf, false); \
                const int nhi = __builtin_amdgcn_update_dpp(hi, hi, CTRL, RM, 0xf, false); \
                const double mv2 = fmin(bits2d(lo, hi), bits2d(nlo, nhi));       \
                d2bits(mv2, lo, hi);                                             \
            }
            MIN_STAGE(0x111, 0xf)   // row_shr:1
            MIN_STAGE(0x112, 0xf)   // row_shr:2
            MIN_STAGE(0x114, 0xf)   // row_shr:4
            MIN_STAGE(0x118, 0xf)   // row_shr:8
            MIN_STAGE(0x142, 0xa)   // row_bcast:15 -> rows 1,3
            MIN_STAGE(0x143, 0xc)   // row_bcast:31 -> rows 2,3
#undef MIN_STAGE
            const int mlo = __builtin_amdgcn_readlane(lo, 63);
            const int mhi = __builtin_amdgcn_readlane(hi, 63);
            const double delta = bits2d(mlo, mhi);   // == min value (scalar)

            // first-index extraction: cd == delta marks min-achievers; lane
            // order == j order within each class; real js (<=128) < dummy js
            int jr = BIG;
            if (cd1 == delta) jr = 2 * lane + 2;
            if (cd0 == delta) jr = 2 * lane + 1;
            int jd = BIG;
            if (cd3 == delta) jd = 2 * lane + 130;
            if (cd2 == delta) jd = 2 * lane + 129;
            const unsigned long long br = __ballot(jr != BIG);
            const unsigned long long bd = __ballot(jd != BIG);
            const unsigned long long bb = br ? br : bd;
            const int cand = (br != 0ull) ? jr : jd;
            j1 = __builtin_amdgcn_readlane(cand, (int)__builtin_ctzll(bb));

            // next row: dummies are never re-matched -> p[j1] = j1-128 statically
            int ol, sl;
            if (j1 >= 129) { ol = (j1 - 129) >> 1; sl = 2 + ((j1 - 129) & 1); }
            else           { ol = (j1 - 1) >> 1;   sl = (j1 - 1) & 1; }
            const int psel = (sl == 0) ? pj0 : (sl == 1) ? pj1 : (sl == 2) ? pj2 : pj3;
            const int i0n = (j1 >= 129) ? (j1 - 128)
                                        : __builtin_amdgcn_readlane(psel, ol);

            // speculative next-row load, issued ASAP (clamped; unused on break)
            const int rown = (i0n > 0 ? i0n : 1) - 1;
            const float2 ccn = *(const float2*)(C_lds + rown * K_ + 2 * lane);

            // ---- shadow work (under the load's latency) ----
            // potential updates (ref order: all used cols + virtual col 0;
            // applied on the final iteration too, before the break — ref-exact)
            usum += delta;
            if (used & 1) { ur0 += delta; v0 -= delta; }
            if (used & 2) { ur1 += delta; v1 -= delta; }
            if (used & 4) { ur2 += delta; v2 -= delta; }
            if (used & 8) { ur3 += delta; v3 -= delta; }

            // u[p[j1]] broadcast from owner's row-start snapshot
            const double usel = (sl == 0) ? up0 : (sl == 1) ? up1 : (sl == 2) ? up2 : up3;
            int ulo, uhi; d2bits(usel, ulo, uhi);
            const double u_n = bits2d(__builtin_amdgcn_readlane(ulo, ol),
                                      __builtin_amdgcn_readlane(uhi, ol));

            if (i0n == 0) break;    // free real column -> augment (way==0)

            // mark j1 used (it is j0 of the next iteration, ref marks at top)
            if (lane == ol) used |= (1 << sl);
            u_i0 = u_n;
            cc = ccn;
        }

        // ---- commit: marked slots write their running u; lane 0 augments
        __syncthreads();
        if (used & 1) u_lds[pj0] = ur0;
        if (used & 2) u_lds[pj1] = ur1;
        if (used & 4) u_lds[pj2] = ur2;
        if (used & 8) u_lds[pj3] = ur3;
        if (lane == 0) { p_lds[j1] = i; u_lds[i] = usum; }
        __syncthreads();
    }

    // out[b][k] = p[k+1] - 1 for the K real columns
    for (int j = lane; j < K_; j += 64)
        out[b * K_ + j] = p_lds[j + 1] - 1;
}

// ------------------------------------------------------------------- launcher
extern "C" void kernel_launch(void* const* d_in, const int* in_sizes, int n_in,
                              void* d_out, int out_size, void* d_ws, size_t ws_size,
                              hipStream_t stream) {
    const float* mp = (const float*)d_in[0];   // meta_points
    const float* mv = (const float*)d_in[1];   // meta_visibles
    /* d_in[2] covisibles: unused by reference */
    const float* gt = (const float*)d_in[3];   // gtpoints
    const float* gv = (const float*)d_in[4];   // gtvisibles
    int* out = (int*)d_out;                    // int32 assignment indices
    float* cost = (float*)d_ws;                // 16*256*128 fp32 = 2 MB

    dim3 gridA(B_, M_);
    cost_kernel<<<gridA, K_, 0, stream>>>(mp, mv, gt, gv, cost);
    match_kernel<<<B_, 64, 0, stream>>>(cost, out);
}